// Round 4
// baseline (681.810 us; speedup 1.0000x reference)
//
#include <hip/hip_runtime.h>
#include <hip/hip_bf16.h>

#define N_ROWS 262144
#define IN_DIM 64
#define HID 256
#define EMB 128
#define OUT_DIM 64
#define NSEG 1024
#define LDS_S 264    // 256 + 8 halves pad
#define CHUNK 1024   // rows per k_scatter block
#define TROWS 128    // LDS h-tile rows
#define NSLOTS (2 * (N_ROWS / CHUNK))   // 512 partial slots

typedef _Float16 h16;
typedef _Float16 h16x8 __attribute__((ext_vector_type(8)));
typedef _Float16 h16x4 __attribute__((ext_vector_type(4)));
typedef float f32x4 __attribute__((ext_vector_type(4)));

// ---------------- prep kernels ----------------

__global__ void k_max(const int* __restrict__ aisle, int* __restrict__ maxA) {
    int v = 0;
    for (int i = blockIdx.x * blockDim.x + threadIdx.x; i < N_ROWS; i += gridDim.x * blockDim.x)
        v = max(v, aisle[i]);
#pragma unroll
    for (int off = 32; off > 0; off >>= 1) v = max(v, __shfl_down(v, off));
    __shared__ int red[4];
    if ((threadIdx.x & 63) == 0) red[threadIdx.x >> 6] = v;
    __syncthreads();
    if (threadIdx.x == 0) {
        int m = red[0];
        for (int i = 1; i < 4; ++i) m = max(m, red[i]);
        atomicMax(maxA, m);
    }
}

__global__ void k_prep_weights(const float* __restrict__ W1, const float* __restrict__ W2,
                               const float* __restrict__ W3, const float* __restrict__ A1f,
                               const float* __restrict__ A2f, const float* __restrict__ A3f,
                               h16* __restrict__ W1t, h16* __restrict__ W2t, h16* __restrict__ W3t,
                               h16* __restrict__ A1t, h16* __restrict__ A2t, h16* __restrict__ A3t) {
    int idx = blockIdx.x * 256 + threadIdx.x;      // total 262144 threads
    if (idx < 16384)       { int o = idx;          int n = o >> 6, k = o & 63;  W1t[o] = (h16)W1[k * 256 + n]; }
    else if (idx < 81920)  { int o = idx - 16384;  int n = o >> 8, k = o & 255; W2t[o] = (h16)W2[k * 256 + n]; }
    else if (idx < 114688) { int o = idx - 81920;  int n = o >> 8, k = o & 255; W3t[o] = (h16)W3[k * 128 + n]; }
    else if (idx < 180224) { int o = idx - 114688; int n = o >> 8, k = o & 255; A1t[o] = (h16)A1f[k * 256 + n]; }
    else if (idx < 245760) { int o = idx - 180224; int n = o >> 8, k = o & 255; A2t[o] = (h16)A2f[k * 256 + n]; }
    else                   { int o = idx - 245760; int n = o >> 8, k = o & 255; A3t[o] = (h16)A3f[k * 64  + n]; }
}

// ---------------- fused MLP layer (in-place LDS, swapped-operand MFMA) ----------------
template <int K, int NOUT, bool ACT>
__device__ __forceinline__ void mlp_layer(const h16* __restrict__ Wt,
                                          const float* __restrict__ bias,
                                          h16* S, int lane, int wave) {
    constexpr int NW = NOUT / 4;   // cols per wave
    constexpr int NT = NW / 16;    // n-tiles per wave
    constexpr int KT = K / 32;     // k-steps
    const int l15 = lane & 15, l4 = lane >> 4;
    f32x4 acc[4][NT];
#pragma unroll
    for (int mt = 0; mt < 4; ++mt)
#pragma unroll
        for (int nt = 0; nt < NT; ++nt)
#pragma unroll
            for (int j = 0; j < 4; ++j) acc[mt][nt][j] = 0.f;

    const h16* wb[NT];
    f32x4 bias4[NT];
#pragma unroll
    for (int nt = 0; nt < NT; ++nt) {
        wb[nt] = Wt + (size_t)(wave * NW + nt * 16 + l15) * K + l4 * 8;
        bias4[nt] = *(const f32x4*)&bias[wave * NW + nt * 16 + l4 * 4];
    }

    h16x8 bc[NT], bn[NT];
#pragma unroll
    for (int nt = 0; nt < NT; ++nt) bn[nt] = *(const h16x8*)wb[nt];

#pragma unroll
    for (int kt = 0; kt < KT; ++kt) {
#pragma unroll
        for (int nt = 0; nt < NT; ++nt) bc[nt] = bn[nt];
        if (kt + 1 < KT) {
#pragma unroll
            for (int nt = 0; nt < NT; ++nt) bn[nt] = *(const h16x8*)(wb[nt] + (kt + 1) * 32);
        }
#pragma unroll
        for (int mt = 0; mt < 4; ++mt) {
            h16x8 a = *(const h16x8*)&S[(mt * 16 + l15) * LDS_S + kt * 32 + l4 * 8];
#pragma unroll
            for (int nt = 0; nt < NT; ++nt)
                acc[mt][nt] = __builtin_amdgcn_mfma_f32_16x16x32_f16(bc[nt], a, acc[mt][nt], 0, 0, 0);
        }
    }
    __syncthreads();   // all reads of S done before in-place overwrite
#pragma unroll
    for (int nt = 0; nt < NT; ++nt) {
        const int cb = wave * NW + nt * 16 + l4 * 4;
#pragma unroll
        for (int mt = 0; mt < 4; ++mt) {
            f32x4 v = acc[mt][nt] + bias4[nt];
            if (ACT) {
#pragma unroll
                for (int j = 0; j < 4; ++j) v[j] = (v[j] > 0.f) ? v[j] : 0.01f * v[j];
            }
            h16x4 hv;
#pragma unroll
            for (int j = 0; j < 4; ++j) hv[j] = (h16)v[j];
            *(h16x4*)&S[(mt * 16 + l15) * LDS_S + cb] = hv;
        }
    }
    __syncthreads();   // new acts visible
}

// ---------------- phase 1: x -> h ----------------
__global__ __launch_bounds__(256) void k1(const float* __restrict__ x,
                                          const h16* __restrict__ W1t, const float* __restrict__ b1,
                                          const h16* __restrict__ W2t, const float* __restrict__ b2,
                                          const h16* __restrict__ W3t, const float* __restrict__ b3,
                                          h16* __restrict__ hbuf) {
    __shared__ __align__(16) h16 S[64 * LDS_S];
    const int tid = threadIdx.x, lane = tid & 63, wave = tid >> 6;
    const int row0 = blockIdx.x * 64;

    for (int i = tid; i < 1024; i += 256) {
        int r = i >> 4, c4 = (i & 15) * 4;
        f32x4 v = *(const f32x4*)&x[(size_t)(row0 + r) * 64 + c4];
        h16* dst = &S[r * LDS_S + c4];
        dst[0] = (h16)v[0]; dst[1] = (h16)v[1]; dst[2] = (h16)v[2]; dst[3] = (h16)v[3];
    }
    __syncthreads();

    mlp_layer<64, 256, true>(W1t, b1, S, lane, wave);
    mlp_layer<256, 256, true>(W2t, b2, S, lane, wave);
    mlp_layer<256, 128, false>(W3t, b3, S, lane, wave);

    for (int i = tid; i < 1024; i += 256) {
        int r = i >> 4, c8 = (i & 15) * 8;
        *(h16x8*)&hbuf[(size_t)(row0 + r) * 128 + c8] = *(const h16x8*)&S[r * LDS_S + c8];
    }
}

// ---------------- phase 2: owner-computes segment sums, atomic-free ----------------
// Thread tid owns (aisle = tid>>2, col-group = tid&3, 32 cols). Scans the block's
// 1024 rows (staged in 128-row LDS tiles); matching rows accumulate into 32 private
// VGPRs. Flush per batch-value slot: non-atomic coalesced stores into
// partials[sid][64][128] + bvmap tag. batch sorted => <=2 values per chunk.
__global__ __launch_bounds__(256) void k_scatter(const h16* __restrict__ hbuf,
                                                 const int* __restrict__ aisle,
                                                 const int* __restrict__ batch,
                                                 float* __restrict__ partials,
                                                 float* __restrict__ pcount,
                                                 int* __restrict__ bvmap) {
    __shared__ __align__(16) h16 T[TROWS * 128];
    __shared__ int la[CHUNK], lb[CHUNK];
    const int tid = threadIdx.x;
    const int row0 = blockIdx.x * CHUNK;

    for (int i = tid; i < CHUNK; i += 256) { la[i] = aisle[row0 + i]; lb[i] = batch[row0 + i]; }
    __syncthreads();

    const int a_own = tid >> 2, cg = tid & 3;
    const int bLo = lb[0], bHi = lb[CHUNK - 1];

    for (int slot = 0; slot < 2; ++slot) {
        const int bv = bLo + slot;
        const int sid = blockIdx.x * 2 + slot;
        if (bv > bHi) { if (tid == 0) bvmap[sid] = -1; continue; }

        float acc[32];
#pragma unroll
        for (int j = 0; j < 32; ++j) acc[j] = 0.f;
        float cnt = 0.f;

        for (int t = 0; t < CHUNK / TROWS; ++t) {
            __syncthreads();   // previous tile fully consumed
            for (int i = tid; i < TROWS * 16; i += 256) {
                int r = i >> 4, c8 = (i & 15) * 8;
                *(h16x8*)&T[r * 128 + c8] =
                    *(const h16x8*)&hbuf[(size_t)(row0 + t * TROWS + r) * 128 + c8];
            }
            __syncthreads();
            const int rbase = t * TROWS;
            for (int r = 0; r < TROWS; ++r) {
                if (la[rbase + r] == a_own && lb[rbase + r] == bv) {
#pragma unroll
                    for (int g2 = 0; g2 < 4; ++g2) {
                        h16x8 hv = *(const h16x8*)&T[r * 128 + cg * 32 + g2 * 8];
#pragma unroll
                        for (int j = 0; j < 8; ++j) acc[g2 * 8 + j] += (float)hv[j];
                    }
                    if (cg == 0) cnt += 1.f;
                }
            }
        }
        // flush: thread tid -> partials[sid][a_own][cg*32..+32] = contiguous 128B
        float* dst = &partials[(size_t)sid * 8192 + tid * 32];
#pragma unroll
        for (int g2 = 0; g2 < 8; ++g2) *(f32x4*)&dst[g2 * 4] = *(const f32x4*)&acc[g2 * 4];
        if (cg == 0) pcount[sid * 64 + a_own] = cnt;
        if (tid == 0) bvmap[sid] = bv;
    }
}

// ---------------- phase 2b: reduce partials -> fp16 means ----------------
// block = (b = blockIdx>>6, a = blockIdx&63), 128 threads = cols
__global__ __launch_bounds__(128) void k_means(const float* __restrict__ partials,
                                               const float* __restrict__ pcount,
                                               const int* __restrict__ bvmap,
                                               h16* __restrict__ means,
                                               const int* __restrict__ maxA) {
    __shared__ int sbv[NSLOTS];
    const int b = blockIdx.x >> 6, a = blockIdx.x & 63;
    const int tid = threadIdx.x;
    const int mult = *maxA + 1;
    for (int i = tid; i < NSLOTS; i += 128) sbv[i] = bvmap[i];
    __syncthreads();
    if (a >= mult) return;

    float sum = 0.f, cnt = 0.f;
    for (int s = 0; s < NSLOTS; ++s) {
        if (sbv[s] == b) {
            sum += partials[(size_t)s * 8192 + a * 128 + tid];
            cnt += pcount[s * 64 + a];   // broadcast load
        }
    }
    means[(size_t)(b * mult + a) * 128 + tid] = (h16)(sum / fmaxf(cnt, 1.0f));
}

// ---------------- phase 3: concat(h, mean) -> out ----------------
__global__ __launch_bounds__(256) void k3(const h16* __restrict__ hbuf,
                                          const int* __restrict__ aisle,
                                          const int* __restrict__ batch,
                                          const h16* __restrict__ means,
                                          const h16* __restrict__ A1t, const float* __restrict__ c1,
                                          const h16* __restrict__ A2t, const float* __restrict__ c2,
                                          const h16* __restrict__ A3t, const float* __restrict__ c3,
                                          float* __restrict__ out, const int* __restrict__ maxA) {
    __shared__ __align__(16) h16 S[64 * LDS_S];
    const int tid = threadIdx.x, lane = tid & 63, wave = tid >> 6;
    const int row0 = blockIdx.x * 64;
    const int mult = *maxA + 1;

    for (int i = tid; i < 1024; i += 256) {
        int r = i >> 4, c8 = (i & 15) * 8;
        *(h16x8*)&S[r * LDS_S + c8] = *(const h16x8*)&hbuf[(size_t)(row0 + r) * 128 + c8];
    }
    {
        const int r = tid >> 2, p = tid & 3;
        const int g = row0 + r;
        const int id = aisle[g] + batch[g] * mult;
        const h16x8* src = (const h16x8*)&means[(size_t)id * 128 + p * 32];
        h16x8* dst = (h16x8*)&S[r * LDS_S + 128 + p * 32];
        dst[0] = src[0]; dst[1] = src[1]; dst[2] = src[2]; dst[3] = src[3];
    }
    __syncthreads();

    mlp_layer<256, 256, true>(A1t, c1, S, lane, wave);
    mlp_layer<256, 256, true>(A2t, c2, S, lane, wave);

    // final layer: K=256 -> 64 cols, swapped operands, fp32 f32x4 stores
    {
        const int l15 = lane & 15, l4 = lane >> 4;
        f32x4 acc4[4];
#pragma unroll
        for (int mt = 0; mt < 4; ++mt)
#pragma unroll
            for (int j = 0; j < 4; ++j) acc4[mt][j] = 0.f;
        const h16* wb = A3t + (size_t)(wave * 16 + l15) * 256 + l4 * 8;
        h16x8 bn = *(const h16x8*)wb, bc;
#pragma unroll
        for (int kt = 0; kt < 8; ++kt) {
            bc = bn;
            if (kt < 7) bn = *(const h16x8*)(wb + (kt + 1) * 32);
#pragma unroll
            for (int mt = 0; mt < 4; ++mt) {
                h16x8 a = *(const h16x8*)&S[(mt * 16 + l15) * LDS_S + kt * 32 + l4 * 8];
                acc4[mt] = __builtin_amdgcn_mfma_f32_16x16x32_f16(bc, a, acc4[mt], 0, 0, 0);
            }
        }
        const f32x4 bias4 = *(const f32x4*)&c3[wave * 16 + l4 * 4];
#pragma unroll
        for (int mt = 0; mt < 4; ++mt) {
            f32x4 v = acc4[mt] + bias4;
            *(f32x4*)&out[(size_t)(row0 + mt * 16 + l15) * 64 + wave * 16 + l4 * 4] = v;
        }
    }
}

// ---------------- host launch ----------------
extern "C" void kernel_launch(void* const* d_in, const int* in_sizes, int n_in,
                              void* d_out, int out_size, void* d_ws, size_t ws_size,
                              hipStream_t stream) {
    const float* x     = (const float*)d_in[0];
    const int*   aisle = (const int*)d_in[1];
    const int*   batch = (const int*)d_in[2];
    const float* W1 = (const float*)d_in[3];  const float* b1 = (const float*)d_in[4];
    const float* W2 = (const float*)d_in[5];  const float* b2 = (const float*)d_in[6];
    const float* W3 = (const float*)d_in[7];  const float* b3 = (const float*)d_in[8];
    const float* A1 = (const float*)d_in[9];  const float* c1 = (const float*)d_in[10];
    const float* A2 = (const float*)d_in[11]; const float* c2 = (const float*)d_in[12];
    const float* A3 = (const float*)d_in[13]; const float* c3 = (const float*)d_in[14];
    float* out = (float*)d_out;

    char* w = (char*)d_ws;
    size_t off = 0;
    h16*   hbuf     = (h16*)(w + off);   off += (size_t)N_ROWS * 128 * sizeof(h16);       // 64 MB
    float* partials = (float*)(w + off); off += (size_t)NSLOTS * 8192 * sizeof(float);    // 16 MB
    float* pcount   = (float*)(w + off); off += NSLOTS * 64 * sizeof(float);
    int*   bvmap    = (int*)(w + off);   off += NSLOTS * sizeof(int);
    h16*   means    = (h16*)(w + off);   off += NSEG * 128 * sizeof(h16);
    h16*   W1t      = (h16*)(w + off);   off += 16384 * sizeof(h16);
    h16*   W2t      = (h16*)(w + off);   off += 65536 * sizeof(h16);
    h16*   W3t      = (h16*)(w + off);   off += 32768 * sizeof(h16);
    h16*   A1t      = (h16*)(w + off);   off += 65536 * sizeof(h16);
    h16*   A2t      = (h16*)(w + off);   off += 65536 * sizeof(h16);
    h16*   A3t      = (h16*)(w + off);   off += 16384 * sizeof(h16);
    int*   maxA     = (int*)(w + off);   off += 256;

    hipMemsetAsync(maxA, 0, sizeof(int), stream);

    k_max<<<256, 256, 0, stream>>>(aisle, maxA);
    k_prep_weights<<<1024, 256, 0, stream>>>(W1, W2, W3, A1, A2, A3, W1t, W2t, W3t, A1t, A2t, A3t);
    k1<<<N_ROWS / 64, 256, 0, stream>>>(x, W1t, b1, W2t, b2, W3t, b3, hbuf);
    k_scatter<<<N_ROWS / CHUNK, 256, 0, stream>>>(hbuf, aisle, batch, partials, pcount, bvmap);
    k_means<<<16 * 64, 128, 0, stream>>>(partials, pcount, bvmap, means, maxA);
    k3<<<N_ROWS / 64, 256, 0, stream>>>(hbuf, aisle, batch, means, A1t, c1, A2t, c2, A3t, c3,
                                        out, maxA);
}

// Round 5
// 487.188 us; speedup vs baseline: 1.3995x; 1.3995x over previous
//
#include <hip/hip_runtime.h>
#include <hip/hip_bf16.h>

#define N_ROWS 262144
#define IN_DIM 64
#define HID 256
#define EMB 128
#define OUT_DIM 64
#define NSEG 1024
#define LDS_S 264    // 256 + 8 halves pad
#define CHUNK 1024   // rows per k_scatter block
#define NSLOTS (2 * (N_ROWS / CHUNK))   // 512 partial slots

typedef _Float16 h16;
typedef _Float16 h16x8 __attribute__((ext_vector_type(8)));
typedef _Float16 h16x4 __attribute__((ext_vector_type(4)));
typedef float f32x4 __attribute__((ext_vector_type(4)));

// ---------------- prep kernels ----------------

__global__ void k_max(const int* __restrict__ aisle, int* __restrict__ maxA) {
    int v = 0;
    for (int i = blockIdx.x * blockDim.x + threadIdx.x; i < N_ROWS; i += gridDim.x * blockDim.x)
        v = max(v, aisle[i]);
#pragma unroll
    for (int off = 32; off > 0; off >>= 1) v = max(v, __shfl_down(v, off));
    __shared__ int red[4];
    if ((threadIdx.x & 63) == 0) red[threadIdx.x >> 6] = v;
    __syncthreads();
    if (threadIdx.x == 0) {
        int m = red[0];
        for (int i = 1; i < 4; ++i) m = max(m, red[i]);
        atomicMax(maxA, m);
    }
}

__global__ void k_prep_weights(const float* __restrict__ W1, const float* __restrict__ W2,
                               const float* __restrict__ W3, const float* __restrict__ A1f,
                               const float* __restrict__ A2f, const float* __restrict__ A3f,
                               h16* __restrict__ W1t, h16* __restrict__ W2t, h16* __restrict__ W3t,
                               h16* __restrict__ A1t, h16* __restrict__ A2t, h16* __restrict__ A3t) {
    int idx = blockIdx.x * 256 + threadIdx.x;      // total 262144 threads
    if (idx < 16384)       { int o = idx;          int n = o >> 6, k = o & 63;  W1t[o] = (h16)W1[k * 256 + n]; }
    else if (idx < 81920)  { int o = idx - 16384;  int n = o >> 8, k = o & 255; W2t[o] = (h16)W2[k * 256 + n]; }
    else if (idx < 114688) { int o = idx - 81920;  int n = o >> 8, k = o & 255; W3t[o] = (h16)W3[k * 128 + n]; }
    else if (idx < 180224) { int o = idx - 114688; int n = o >> 8, k = o & 255; A1t[o] = (h16)A1f[k * 256 + n]; }
    else if (idx < 245760) { int o = idx - 180224; int n = o >> 8, k = o & 255; A2t[o] = (h16)A2f[k * 256 + n]; }
    else                   { int o = idx - 245760; int n = o >> 8, k = o & 255; A3t[o] = (h16)A3f[k * 64  + n]; }
}

// ---------------- fused MLP layer (in-place LDS, swapped-operand MFMA) ----------------
template <int K, int NOUT, bool ACT>
__device__ __forceinline__ void mlp_layer(const h16* __restrict__ Wt,
                                          const float* __restrict__ bias,
                                          h16* S, int lane, int wave) {
    constexpr int NW = NOUT / 4;   // cols per wave
    constexpr int NT = NW / 16;    // n-tiles per wave
    constexpr int KT = K / 32;     // k-steps
    const int l15 = lane & 15, l4 = lane >> 4;
    f32x4 acc[4][NT];
#pragma unroll
    for (int mt = 0; mt < 4; ++mt)
#pragma unroll
        for (int nt = 0; nt < NT; ++nt)
#pragma unroll
            for (int j = 0; j < 4; ++j) acc[mt][nt][j] = 0.f;

    const h16* wb[NT];
    f32x4 bias4[NT];
#pragma unroll
    for (int nt = 0; nt < NT; ++nt) {
        wb[nt] = Wt + (size_t)(wave * NW + nt * 16 + l15) * K + l4 * 8;
        bias4[nt] = *(const f32x4*)&bias[wave * NW + nt * 16 + l4 * 4];
    }

    h16x8 bc[NT], bn[NT];
#pragma unroll
    for (int nt = 0; nt < NT; ++nt) bn[nt] = *(const h16x8*)wb[nt];

#pragma unroll
    for (int kt = 0; kt < KT; ++kt) {
#pragma unroll
        for (int nt = 0; nt < NT; ++nt) bc[nt] = bn[nt];
        if (kt + 1 < KT) {
#pragma unroll
            for (int nt = 0; nt < NT; ++nt) bn[nt] = *(const h16x8*)(wb[nt] + (kt + 1) * 32);
        }
#pragma unroll
        for (int mt = 0; mt < 4; ++mt) {
            h16x8 a = *(const h16x8*)&S[(mt * 16 + l15) * LDS_S + kt * 32 + l4 * 8];
#pragma unroll
            for (int nt = 0; nt < NT; ++nt)
                acc[mt][nt] = __builtin_amdgcn_mfma_f32_16x16x32_f16(bc[nt], a, acc[mt][nt], 0, 0, 0);
        }
    }
    __syncthreads();   // all reads of S done before in-place overwrite
#pragma unroll
    for (int nt = 0; nt < NT; ++nt) {
        const int cb = wave * NW + nt * 16 + l4 * 4;
#pragma unroll
        for (int mt = 0; mt < 4; ++mt) {
            f32x4 v = acc[mt][nt] + bias4[nt];
            if (ACT) {
#pragma unroll
                for (int j = 0; j < 4; ++j) v[j] = (v[j] > 0.f) ? v[j] : 0.01f * v[j];
            }
            h16x4 hv;
#pragma unroll
            for (int j = 0; j < 4; ++j) hv[j] = (h16)v[j];
            *(h16x4*)&S[(mt * 16 + l15) * LDS_S + cb] = hv;
        }
    }
    __syncthreads();   // new acts visible
}

// ---------------- phase 1: x -> h ----------------
__global__ __launch_bounds__(256) void k1(const float* __restrict__ x,
                                          const h16* __restrict__ W1t, const float* __restrict__ b1,
                                          const h16* __restrict__ W2t, const float* __restrict__ b2,
                                          const h16* __restrict__ W3t, const float* __restrict__ b3,
                                          h16* __restrict__ hbuf) {
    __shared__ __align__(16) h16 S[64 * LDS_S];
    const int tid = threadIdx.x, lane = tid & 63, wave = tid >> 6;
    const int row0 = blockIdx.x * 64;

    for (int i = tid; i < 1024; i += 256) {
        int r = i >> 4, c4 = (i & 15) * 4;
        f32x4 v = *(const f32x4*)&x[(size_t)(row0 + r) * 64 + c4];
        h16* dst = &S[r * LDS_S + c4];
        dst[0] = (h16)v[0]; dst[1] = (h16)v[1]; dst[2] = (h16)v[2]; dst[3] = (h16)v[3];
    }
    __syncthreads();

    mlp_layer<64, 256, true>(W1t, b1, S, lane, wave);
    mlp_layer<256, 256, true>(W2t, b2, S, lane, wave);
    mlp_layer<256, 128, false>(W3t, b3, S, lane, wave);

    for (int i = tid; i < 1024; i += 256) {
        int r = i >> 4, c8 = (i & 15) * 8;
        *(h16x8*)&hbuf[(size_t)(row0 + r) * 128 + c8] = *(const h16x8*)&S[r * LDS_S + c8];
    }
}

// ---------------- phase 2: counting-sort + owner-computes segment sums ----------------
// Block owns CHUNK contiguous rows. Counting sort rows by bin=(slot,aisle) in LDS
// (hist atomics give per-row rank, Hillis-Steele prefix over 128 bins, scatter ids
// into rowlist). Thread (aisle=tid>>2, colgroup=tid&3) then visits ONLY its own
// rows via rowlist, accumulating 32 cols in VGPRs. Atomic-free flush into
// partials[sid][64][128] (coalesced) + count from prefix sums. batch sorted =>
// <=2 batch values per chunk (slot = min(b-bLo,1)).
__global__ __launch_bounds__(256) void k_scatter(const h16* __restrict__ hbuf,
                                                 const int* __restrict__ aisle,
                                                 const int* __restrict__ batch,
                                                 float* __restrict__ partials,
                                                 float* __restrict__ pcount,
                                                 int* __restrict__ bvmap) {
    __shared__ int la[CHUNK], lb[CHUNK], rankv[CHUNK], rowlist[CHUNK];
    __shared__ int hist[128], scan[128];
    const int tid = threadIdx.x;
    const int row0 = blockIdx.x * CHUNK;

    if (tid < 128) hist[tid] = 0;
    for (int i = tid; i < CHUNK; i += 256) { la[i] = aisle[row0 + i]; lb[i] = batch[row0 + i]; }
    __syncthreads();

    const int bLo = lb[0], bHi = lb[CHUNK - 1];

    // histogram + per-row rank
    for (int i = tid; i < CHUNK; i += 256) {
        int slot = min(lb[i] - bLo, 1);
        rankv[i] = atomicAdd(&hist[slot * 64 + la[i]], 1);
    }
    __syncthreads();
    if (tid < 128) scan[tid] = hist[tid];
    __syncthreads();
#pragma unroll
    for (int st = 1; st < 128; st <<= 1) {
        int v = 0;
        if (tid < 128 && tid >= st) v = scan[tid - st];
        __syncthreads();
        if (tid < 128) scan[tid] += v;
        __syncthreads();
    }
    // scatter row ids into sorted list: start(bin) = scan[bin] - hist[bin]
    for (int i = tid; i < CHUNK; i += 256) {
        int bin = min(lb[i] - bLo, 1) * 64 + la[i];
        rowlist[scan[bin] - hist[bin] + rankv[i]] = i;
    }
    __syncthreads();

    const int a_own = tid >> 2, cg = tid & 3;
    for (int slot = 0; slot < 2; ++slot) {
        const int sid = blockIdx.x * 2 + slot;
        const int bv = bLo + slot;
        if (bv > bHi) { if (tid == 0) bvmap[sid] = -1; continue; }

        const int bin = slot * 64 + a_own;
        const int s1 = scan[bin];
        const int s0 = s1 - hist[bin];

        float acc[32];
#pragma unroll
        for (int j = 0; j < 32; ++j) acc[j] = 0.f;

        for (int idx = s0; idx < s1; ++idx) {
            const int r = rowlist[idx];
            const h16x8* src = (const h16x8*)&hbuf[(size_t)(row0 + r) * 128 + cg * 32];
            h16x8 v0 = src[0], v1 = src[1], v2 = src[2], v3 = src[3];
#pragma unroll
            for (int j = 0; j < 8; ++j) {
                acc[j]      += (float)v0[j];
                acc[8 + j]  += (float)v1[j];
                acc[16 + j] += (float)v2[j];
                acc[24 + j] += (float)v3[j];
            }
        }
        // flush: thread tid -> partials[sid][a_own][cg*32..+32] (contiguous 128B)
        float* dst = &partials[(size_t)sid * 8192 + tid * 32];
#pragma unroll
        for (int g2 = 0; g2 < 8; ++g2) *(f32x4*)&dst[g2 * 4] = *(const f32x4*)&acc[g2 * 4];
        if (cg == 0) pcount[sid * 64 + a_own] = (float)(s1 - s0);
        if (tid == 0) bvmap[sid] = bv;
    }
}

// ---------------- phase 2b: reduce partials -> fp16 means ----------------
// block = (b = blockIdx>>6, a = blockIdx&63), 128 threads = cols
__global__ __launch_bounds__(128) void k_means(const float* __restrict__ partials,
                                               const float* __restrict__ pcount,
                                               const int* __restrict__ bvmap,
                                               h16* __restrict__ means,
                                               const int* __restrict__ maxA) {
    __shared__ int sbv[NSLOTS];
    const int b = blockIdx.x >> 6, a = blockIdx.x & 63;
    const int tid = threadIdx.x;
    const int mult = *maxA + 1;
    for (int i = tid; i < NSLOTS; i += 128) sbv[i] = bvmap[i];
    __syncthreads();
    if (a >= mult) return;

    float sum = 0.f, cnt = 0.f;
    for (int s = 0; s < NSLOTS; ++s) {
        if (sbv[s] == b) {
            sum += partials[(size_t)s * 8192 + a * 128 + tid];
            cnt += pcount[s * 64 + a];   // broadcast load
        }
    }
    means[(size_t)(b * mult + a) * 128 + tid] = (h16)(sum / fmaxf(cnt, 1.0f));
}

// ---------------- phase 3: concat(h, mean) -> out ----------------
__global__ __launch_bounds__(256) void k3(const h16* __restrict__ hbuf,
                                          const int* __restrict__ aisle,
                                          const int* __restrict__ batch,
                                          const h16* __restrict__ means,
                                          const h16* __restrict__ A1t, const float* __restrict__ c1,
                                          const h16* __restrict__ A2t, const float* __restrict__ c2,
                                          const h16* __restrict__ A3t, const float* __restrict__ c3,
                                          float* __restrict__ out, const int* __restrict__ maxA) {
    __shared__ __align__(16) h16 S[64 * LDS_S];
    const int tid = threadIdx.x, lane = tid & 63, wave = tid >> 6;
    const int row0 = blockIdx.x * 64;
    const int mult = *maxA + 1;

    for (int i = tid; i < 1024; i += 256) {
        int r = i >> 4, c8 = (i & 15) * 8;
        *(h16x8*)&S[r * LDS_S + c8] = *(const h16x8*)&hbuf[(size_t)(row0 + r) * 128 + c8];
    }
    {
        const int r = tid >> 2, p = tid & 3;
        const int g = row0 + r;
        const int id = aisle[g] + batch[g] * mult;
        const h16x8* src = (const h16x8*)&means[(size_t)id * 128 + p * 32];
        h16x8* dst = (h16x8*)&S[r * LDS_S + 128 + p * 32];
        dst[0] = src[0]; dst[1] = src[1]; dst[2] = src[2]; dst[3] = src[3];
    }
    __syncthreads();

    mlp_layer<256, 256, true>(A1t, c1, S, lane, wave);
    mlp_layer<256, 256, true>(A2t, c2, S, lane, wave);

    // final layer: K=256 -> 64 cols, swapped operands, fp32 f32x4 stores
    {
        const int l15 = lane & 15, l4 = lane >> 4;
        f32x4 acc4[4];
#pragma unroll
        for (int mt = 0; mt < 4; ++mt)
#pragma unroll
            for (int j = 0; j < 4; ++j) acc4[mt][j] = 0.f;
        const h16* wb = A3t + (size_t)(wave * 16 + l15) * 256 + l4 * 8;
        h16x8 bn = *(const h16x8*)wb, bc;
#pragma unroll
        for (int kt = 0; kt < 8; ++kt) {
            bc = bn;
            if (kt < 7) bn = *(const h16x8*)(wb + (kt + 1) * 32);
#pragma unroll
            for (int mt = 0; mt < 4; ++mt) {
                h16x8 a = *(const h16x8*)&S[(mt * 16 + l15) * LDS_S + kt * 32 + l4 * 8];
                acc4[mt] = __builtin_amdgcn_mfma_f32_16x16x32_f16(bc, a, acc4[mt], 0, 0, 0);
            }
        }
        const f32x4 bias4 = *(const f32x4*)&c3[wave * 16 + l4 * 4];
#pragma unroll
        for (int mt = 0; mt < 4; ++mt) {
            f32x4 v = acc4[mt] + bias4;
            *(f32x4*)&out[(size_t)(row0 + mt * 16 + l15) * 64 + wave * 16 + l4 * 4] = v;
        }
    }
}

// ---------------- host launch ----------------
extern "C" void kernel_launch(void* const* d_in, const int* in_sizes, int n_in,
                              void* d_out, int out_size, void* d_ws, size_t ws_size,
                              hipStream_t stream) {
    const float* x     = (const float*)d_in[0];
    const int*   aisle = (const int*)d_in[1];
    const int*   batch = (const int*)d_in[2];
    const float* W1 = (const float*)d_in[3];  const float* b1 = (const float*)d_in[4];
    const float* W2 = (const float*)d_in[5];  const float* b2 = (const float*)d_in[6];
    const float* W3 = (const float*)d_in[7];  const float* b3 = (const float*)d_in[8];
    const float* A1 = (const float*)d_in[9];  const float* c1 = (const float*)d_in[10];
    const float* A2 = (const float*)d_in[11]; const float* c2 = (const float*)d_in[12];
    const float* A3 = (const float*)d_in[13]; const float* c3 = (const float*)d_in[14];
    float* out = (float*)d_out;

    char* w = (char*)d_ws;
    size_t off = 0;
    h16*   hbuf     = (h16*)(w + off);   off += (size_t)N_ROWS * 128 * sizeof(h16);       // 64 MB
    float* partials = (float*)(w + off); off += (size_t)NSLOTS * 8192 * sizeof(float);    // 16 MB
    float* pcount   = (float*)(w + off); off += NSLOTS * 64 * sizeof(float);
    int*   bvmap    = (int*)(w + off);   off += NSLOTS * sizeof(int);
    h16*   means    = (h16*)(w + off);   off += NSEG * 128 * sizeof(h16);
    h16*   W1t      = (h16*)(w + off);   off += 16384 * sizeof(h16);
    h16*   W2t      = (h16*)(w + off);   off += 65536 * sizeof(h16);
    h16*   W3t      = (h16*)(w + off);   off += 32768 * sizeof(h16);
    h16*   A1t      = (h16*)(w + off);   off += 65536 * sizeof(h16);
    h16*   A2t      = (h16*)(w + off);   off += 65536 * sizeof(h16);
    h16*   A3t      = (h16*)(w + off);   off += 16384 * sizeof(h16);
    int*   maxA     = (int*)(w + off);   off += 256;

    hipMemsetAsync(maxA, 0, sizeof(int), stream);

    k_max<<<256, 256, 0, stream>>>(aisle, maxA);
    k_prep_weights<<<1024, 256, 0, stream>>>(W1, W2, W3, A1, A2, A3, W1t, W2t, W3t, A1t, A2t, A3t);
    k1<<<N_ROWS / 64, 256, 0, stream>>>(x, W1t, b1, W2t, b2, W3t, b3, hbuf);
    k_scatter<<<N_ROWS / CHUNK, 256, 0, stream>>>(hbuf, aisle, batch, partials, pcount, bvmap);
    k_means<<<16 * 64, 128, 0, stream>>>(partials, pcount, bvmap, means, maxA);
    k3<<<N_ROWS / 64, 256, 0, stream>>>(hbuf, aisle, batch, means, A1t, c1, A2t, c2, A3t, c3,
                                        out, maxA);
}

// Round 6
// 480.146 us; speedup vs baseline: 1.4200x; 1.0147x over previous
//
#include <hip/hip_runtime.h>
#include <hip/hip_bf16.h>

#define N_ROWS 262144
#define IN_DIM 64
#define HID 256
#define EMB 128
#define OUT_DIM 64
#define NSEG 1024
#define LDS_S 264    // 256 + 8 halves pad
#define CHUNK 1024   // rows per k_scatter block
#define NSLOTS (2 * (N_ROWS / CHUNK))   // 512 partial slots

typedef _Float16 h16;
typedef _Float16 h16x8 __attribute__((ext_vector_type(8)));
typedef _Float16 h16x4 __attribute__((ext_vector_type(4)));
typedef float f32x4 __attribute__((ext_vector_type(4)));

// ---------------- prep kernels ----------------

__global__ void k_max(const int* __restrict__ aisle, int* __restrict__ maxA) {
    int v = 0;
    for (int i = blockIdx.x * blockDim.x + threadIdx.x; i < N_ROWS; i += gridDim.x * blockDim.x)
        v = max(v, aisle[i]);
#pragma unroll
    for (int off = 32; off > 0; off >>= 1) v = max(v, __shfl_down(v, off));
    __shared__ int red[4];
    if ((threadIdx.x & 63) == 0) red[threadIdx.x >> 6] = v;
    __syncthreads();
    if (threadIdx.x == 0) {
        int m = red[0];
        for (int i = 1; i < 4; ++i) m = max(m, red[i]);
        atomicMax(maxA, m);
    }
}

__global__ void k_prep_weights(const float* __restrict__ W1, const float* __restrict__ W2,
                               const float* __restrict__ W3, const float* __restrict__ A1f,
                               const float* __restrict__ A2f, const float* __restrict__ A3f,
                               h16* __restrict__ W1t, h16* __restrict__ W2t, h16* __restrict__ W3t,
                               h16* __restrict__ A1t, h16* __restrict__ A2t, h16* __restrict__ A3t) {
    int idx = blockIdx.x * 256 + threadIdx.x;      // total 262144 threads
    if (idx < 16384)       { int o = idx;          int n = o >> 6, k = o & 63;  W1t[o] = (h16)W1[k * 256 + n]; }
    else if (idx < 81920)  { int o = idx - 16384;  int n = o >> 8, k = o & 255; W2t[o] = (h16)W2[k * 256 + n]; }
    else if (idx < 114688) { int o = idx - 81920;  int n = o >> 8, k = o & 255; W3t[o] = (h16)W3[k * 128 + n]; }
    else if (idx < 180224) { int o = idx - 114688; int n = o >> 8, k = o & 255; A1t[o] = (h16)A1f[k * 256 + n]; }
    else if (idx < 245760) { int o = idx - 180224; int n = o >> 8, k = o & 255; A2t[o] = (h16)A2f[k * 256 + n]; }
    else                   { int o = idx - 245760; int n = o >> 8, k = o & 255; A3t[o] = (h16)A3f[k * 64  + n]; }
}

// ---------------- fused MLP layer (ping-pong LDS, 1 barrier, depth-2 B prefetch) ----------------
// Sin: [64 rows][K] fp16, stride LDS_S. Computes lrelu?(Sin @ Wt^T + bias) into
// Sout[64][NOUT]. Wt is [NOUT][K] fp16. Swapped-operand MFMA: mfma(w, a, acc) ->
// D[n][m], lane's 4 regs = 4 consecutive weight cols, col index = act row.
// B-frags double-prefetched (b0 in use, b1 = kt+1 in regs, kt+2 in flight).
template <int K, int NOUT, bool ACT>
__device__ __forceinline__ void mlp_layer(const h16* __restrict__ Wt,
                                          const float* __restrict__ bias,
                                          const h16* __restrict__ Sin,
                                          h16* __restrict__ Sout,
                                          int lane, int wave) {
    constexpr int NW = NOUT / 4;   // cols per wave
    constexpr int NT = NW / 16;    // n-tiles per wave
    constexpr int KT = K / 32;     // k-steps
    const int l15 = lane & 15, l4 = lane >> 4;
    f32x4 acc[4][NT];
#pragma unroll
    for (int mt = 0; mt < 4; ++mt)
#pragma unroll
        for (int nt = 0; nt < NT; ++nt)
#pragma unroll
            for (int j = 0; j < 4; ++j) acc[mt][nt][j] = 0.f;

    const h16* wb[NT];
    f32x4 bias4[NT];
#pragma unroll
    for (int nt = 0; nt < NT; ++nt) {
        wb[nt] = Wt + (size_t)(wave * NW + nt * 16 + l15) * K + l4 * 8;
        bias4[nt] = *(const f32x4*)&bias[wave * NW + nt * 16 + l4 * 4];
    }

    h16x8 b0[NT], b1[NT];
#pragma unroll
    for (int nt = 0; nt < NT; ++nt) b0[nt] = *(const h16x8*)wb[nt];
    if (KT > 1) {
#pragma unroll
        for (int nt = 0; nt < NT; ++nt) b1[nt] = *(const h16x8*)(wb[nt] + 32);
    }

#pragma unroll
    for (int kt = 0; kt < KT; ++kt) {
        h16x8 bc[NT];
#pragma unroll
        for (int nt = 0; nt < NT; ++nt) bc[nt] = b0[nt];
#pragma unroll
        for (int nt = 0; nt < NT; ++nt) b0[nt] = b1[nt];
        if (kt + 2 < KT) {
#pragma unroll
            for (int nt = 0; nt < NT; ++nt) b1[nt] = *(const h16x8*)(wb[nt] + (kt + 2) * 32);
        }
        h16x8 a[4];
#pragma unroll
        for (int mt = 0; mt < 4; ++mt)
            a[mt] = *(const h16x8*)&Sin[(mt * 16 + l15) * LDS_S + kt * 32 + l4 * 8];
#pragma unroll
        for (int mt = 0; mt < 4; ++mt)
#pragma unroll
            for (int nt = 0; nt < NT; ++nt)
                acc[mt][nt] = __builtin_amdgcn_mfma_f32_16x16x32_f16(bc[nt], a[mt], acc[mt][nt], 0, 0, 0);
    }

    // epilogue: write Sout (no prior barrier needed -- Sout is the other buffer)
#pragma unroll
    for (int nt = 0; nt < NT; ++nt) {
        const int cb = wave * NW + nt * 16 + l4 * 4;
#pragma unroll
        for (int mt = 0; mt < 4; ++mt) {
            f32x4 v = acc[mt][nt] + bias4[nt];
            if (ACT) {
#pragma unroll
                for (int j = 0; j < 4; ++j) v[j] = (v[j] > 0.f) ? v[j] : 0.01f * v[j];
            }
            h16x4 hv;
#pragma unroll
            for (int j = 0; j < 4; ++j) hv[j] = (h16)v[j];
            *(h16x4*)&Sout[(mt * 16 + l15) * LDS_S + cb] = hv;
        }
    }
    __syncthreads();   // new acts visible; also guarantees Sin reads done before next layer overwrites it
}

// ---------------- phase 1: x -> h ----------------
__global__ __launch_bounds__(256) void k1(const float* __restrict__ x,
                                          const h16* __restrict__ W1t, const float* __restrict__ b1,
                                          const h16* __restrict__ W2t, const float* __restrict__ b2,
                                          const h16* __restrict__ W3t, const float* __restrict__ b3,
                                          h16* __restrict__ hbuf) {
    __shared__ __align__(16) h16 S0[64 * LDS_S];
    __shared__ __align__(16) h16 S1[64 * LDS_S];
    const int tid = threadIdx.x, lane = tid & 63, wave = tid >> 6;
    const int row0 = blockIdx.x * 64;

    for (int i = tid; i < 1024; i += 256) {
        int r = i >> 4, c4 = (i & 15) * 4;
        f32x4 v = *(const f32x4*)&x[(size_t)(row0 + r) * 64 + c4];
        h16* dst = &S0[r * LDS_S + c4];
        dst[0] = (h16)v[0]; dst[1] = (h16)v[1]; dst[2] = (h16)v[2]; dst[3] = (h16)v[3];
    }
    __syncthreads();

    mlp_layer<64, 256, true>(W1t, b1, S0, S1, lane, wave);
    mlp_layer<256, 256, true>(W2t, b2, S1, S0, lane, wave);
    mlp_layer<256, 128, false>(W3t, b3, S0, S1, lane, wave);

    for (int i = tid; i < 1024; i += 256) {
        int r = i >> 4, c8 = (i & 15) * 8;
        *(h16x8*)&hbuf[(size_t)(row0 + r) * 128 + c8] = *(const h16x8*)&S1[r * LDS_S + c8];
    }
}

// ---------------- phase 2: counting-sort + owner-computes segment sums ----------------
__global__ __launch_bounds__(256) void k_scatter(const h16* __restrict__ hbuf,
                                                 const int* __restrict__ aisle,
                                                 const int* __restrict__ batch,
                                                 float* __restrict__ partials,
                                                 float* __restrict__ pcount,
                                                 int* __restrict__ bvmap) {
    __shared__ int la[CHUNK], lb[CHUNK], rankv[CHUNK], rowlist[CHUNK];
    __shared__ int hist[128], scan[128];
    const int tid = threadIdx.x;
    const int row0 = blockIdx.x * CHUNK;

    if (tid < 128) hist[tid] = 0;
    for (int i = tid; i < CHUNK; i += 256) { la[i] = aisle[row0 + i]; lb[i] = batch[row0 + i]; }
    __syncthreads();

    const int bLo = lb[0], bHi = lb[CHUNK - 1];

    for (int i = tid; i < CHUNK; i += 256) {
        int slot = min(lb[i] - bLo, 1);
        rankv[i] = atomicAdd(&hist[slot * 64 + la[i]], 1);
    }
    __syncthreads();
    if (tid < 128) scan[tid] = hist[tid];
    __syncthreads();
#pragma unroll
    for (int st = 1; st < 128; st <<= 1) {
        int v = 0;
        if (tid < 128 && tid >= st) v = scan[tid - st];
        __syncthreads();
        if (tid < 128) scan[tid] += v;
        __syncthreads();
    }
    for (int i = tid; i < CHUNK; i += 256) {
        int bin = min(lb[i] - bLo, 1) * 64 + la[i];
        rowlist[scan[bin] - hist[bin] + rankv[i]] = i;
    }
    __syncthreads();

    const int a_own = tid >> 2, cg = tid & 3;
    for (int slot = 0; slot < 2; ++slot) {
        const int sid = blockIdx.x * 2 + slot;
        const int bv = bLo + slot;
        if (bv > bHi) { if (tid == 0) bvmap[sid] = -1; continue; }

        const int bin = slot * 64 + a_own;
        const int s1 = scan[bin];
        const int s0 = s1 - hist[bin];

        float acc[32];
#pragma unroll
        for (int j = 0; j < 32; ++j) acc[j] = 0.f;

        for (int idx = s0; idx < s1; ++idx) {
            const int r = rowlist[idx];
            const h16x8* src = (const h16x8*)&hbuf[(size_t)(row0 + r) * 128 + cg * 32];
            h16x8 v0 = src[0], v1 = src[1], v2 = src[2], v3 = src[3];
#pragma unroll
            for (int j = 0; j < 8; ++j) {
                acc[j]      += (float)v0[j];
                acc[8 + j]  += (float)v1[j];
                acc[16 + j] += (float)v2[j];
                acc[24 + j] += (float)v3[j];
            }
        }
        float* dst = &partials[(size_t)sid * 8192 + tid * 32];
#pragma unroll
        for (int g2 = 0; g2 < 8; ++g2) *(f32x4*)&dst[g2 * 4] = *(const f32x4*)&acc[g2 * 4];
        if (cg == 0) pcount[sid * 64 + a_own] = (float)(s1 - s0);
        if (tid == 0) bvmap[sid] = bv;
    }
}

// ---------------- phase 2b: reduce partials -> fp16 means ----------------
__global__ __launch_bounds__(128) void k_means(const float* __restrict__ partials,
                                               const float* __restrict__ pcount,
                                               const int* __restrict__ bvmap,
                                               h16* __restrict__ means,
                                               const int* __restrict__ maxA) {
    __shared__ int sbv[NSLOTS];
    const int b = blockIdx.x >> 6, a = blockIdx.x & 63;
    const int tid = threadIdx.x;
    const int mult = *maxA + 1;
    for (int i = tid; i < NSLOTS; i += 128) sbv[i] = bvmap[i];
    __syncthreads();
    if (a >= mult) return;

    float sum = 0.f, cnt = 0.f;
    for (int s = 0; s < NSLOTS; ++s) {
        if (sbv[s] == b) {
            sum += partials[(size_t)s * 8192 + a * 128 + tid];
            cnt += pcount[s * 64 + a];   // broadcast load
        }
    }
    means[(size_t)(b * mult + a) * 128 + tid] = (h16)(sum / fmaxf(cnt, 1.0f));
}

// ---------------- phase 3: concat(h, mean) -> out ----------------
__global__ __launch_bounds__(256) void k3(const h16* __restrict__ hbuf,
                                          const int* __restrict__ aisle,
                                          const int* __restrict__ batch,
                                          const h16* __restrict__ means,
                                          const h16* __restrict__ A1t, const float* __restrict__ c1,
                                          const h16* __restrict__ A2t, const float* __restrict__ c2,
                                          const h16* __restrict__ A3t, const float* __restrict__ c3,
                                          float* __restrict__ out, const int* __restrict__ maxA) {
    __shared__ __align__(16) h16 S0[64 * LDS_S];
    __shared__ __align__(16) h16 S1[64 * LDS_S];
    const int tid = threadIdx.x, lane = tid & 63, wave = tid >> 6;
    const int row0 = blockIdx.x * 64;
    const int mult = *maxA + 1;

    for (int i = tid; i < 1024; i += 256) {
        int r = i >> 4, c8 = (i & 15) * 8;
        *(h16x8*)&S0[r * LDS_S + c8] = *(const h16x8*)&hbuf[(size_t)(row0 + r) * 128 + c8];
    }
    {
        const int r = tid >> 2, p = tid & 3;
        const int g = row0 + r;
        const int id = aisle[g] + batch[g] * mult;
        const h16x8* src = (const h16x8*)&means[(size_t)id * 128 + p * 32];
        h16x8* dst = (h16x8*)&S0[r * LDS_S + 128 + p * 32];
        dst[0] = src[0]; dst[1] = src[1]; dst[2] = src[2]; dst[3] = src[3];
    }
    __syncthreads();

    mlp_layer<256, 256, true>(A1t, c1, S0, S1, lane, wave);
    mlp_layer<256, 256, true>(A2t, c2, S1, S0, lane, wave);

    // final layer: K=256 -> 64 cols, depth-2 prefetch, fp32 f32x4 stores
    {
        const int l15 = lane & 15, l4 = lane >> 4;
        f32x4 acc4[4];
#pragma unroll
        for (int mt = 0; mt < 4; ++mt)
#pragma unroll
            for (int j = 0; j < 4; ++j) acc4[mt][j] = 0.f;
        const h16* wb = A3t + (size_t)(wave * 16 + l15) * 256 + l4 * 8;
        h16x8 b0 = *(const h16x8*)wb;
        h16x8 b1 = *(const h16x8*)(wb + 32);
#pragma unroll
        for (int kt = 0; kt < 8; ++kt) {
            h16x8 bc = b0;
            b0 = b1;
            if (kt + 2 < 8) b1 = *(const h16x8*)(wb + (kt + 2) * 32);
#pragma unroll
            for (int mt = 0; mt < 4; ++mt) {
                h16x8 a = *(const h16x8*)&S0[(mt * 16 + l15) * LDS_S + kt * 32 + l4 * 8];
                acc4[mt] = __builtin_amdgcn_mfma_f32_16x16x32_f16(bc, a, acc4[mt], 0, 0, 0);
            }
        }
        const f32x4 bias4 = *(const f32x4*)&c3[wave * 16 + l4 * 4];
#pragma unroll
        for (int mt = 0; mt < 4; ++mt) {
            f32x4 v = acc4[mt] + bias4;
            *(f32x4*)&out[(size_t)(row0 + mt * 16 + l15) * 64 + wave * 16 + l4 * 4] = v;
        }
    }
}

// ---------------- host launch ----------------
extern "C" void kernel_launch(void* const* d_in, const int* in_sizes, int n_in,
                              void* d_out, int out_size, void* d_ws, size_t ws_size,
                              hipStream_t stream) {
    const float* x     = (const float*)d_in[0];
    const int*   aisle = (const int*)d_in[1];
    const int*   batch = (const int*)d_in[2];
    const float* W1 = (const float*)d_in[3];  const float* b1 = (const float*)d_in[4];
    const float* W2 = (const float*)d_in[5];  const float* b2 = (const float*)d_in[6];
    const float* W3 = (const float*)d_in[7];  const float* b3 = (const float*)d_in[8];
    const float* A1 = (const float*)d_in[9];  const float* c1 = (const float*)d_in[10];
    const float* A2 = (const float*)d_in[11]; const float* c2 = (const float*)d_in[12];
    const float* A3 = (const float*)d_in[13]; const float* c3 = (const float*)d_in[14];
    float* out = (float*)d_out;

    char* w = (char*)d_ws;
    size_t off = 0;
    h16*   hbuf     = (h16*)(w + off);   off += (size_t)N_ROWS * 128 * sizeof(h16);       // 64 MB
    float* partials = (float*)(w + off); off += (size_t)NSLOTS * 8192 * sizeof(float);    // 16 MB
    float* pcount   = (float*)(w + off); off += NSLOTS * 64 * sizeof(float);
    int*   bvmap    = (int*)(w + off);   off += NSLOTS * sizeof(int);
    h16*   means    = (h16*)(w + off);   off += NSEG * 128 * sizeof(h16);
    h16*   W1t      = (h16*)(w + off);   off += 16384 * sizeof(h16);
    h16*   W2t      = (h16*)(w + off);   off += 65536 * sizeof(h16);
    h16*   W3t      = (h16*)(w + off);   off += 32768 * sizeof(h16);
    h16*   A1t      = (h16*)(w + off);   off += 65536 * sizeof(h16);
    h16*   A2t      = (h16*)(w + off);   off += 65536 * sizeof(h16);
    h16*   A3t      = (h16*)(w + off);   off += 16384 * sizeof(h16);
    int*   maxA     = (int*)(w + off);   off += 256;

    hipMemsetAsync(maxA, 0, sizeof(int), stream);

    k_max<<<256, 256, 0, stream>>>(aisle, maxA);
    k_prep_weights<<<1024, 256, 0, stream>>>(W1, W2, W3, A1, A2, A3, W1t, W2t, W3t, A1t, A2t, A3t);
    k1<<<N_ROWS / 64, 256, 0, stream>>>(x, W1t, b1, W2t, b2, W3t, b3, hbuf);
    k_scatter<<<N_ROWS / CHUNK, 256, 0, stream>>>(hbuf, aisle, batch, partials, pcount, bvmap);
    k_means<<<16 * 64, 128, 0, stream>>>(partials, pcount, bvmap, means, maxA);
    k3<<<N_ROWS / 64, 256, 0, stream>>>(hbuf, aisle, batch, means, A1t, c1, A2t, c2, A3t, c3,
                                        out, maxA);
}